// Round 1
// baseline (1946.051 us; speedup 1.0000x reference)
//
#include <hip/hip_runtime.h>
#include <math.h>

#define B_   2
#define D_   2048   // d_inner
#define L_   2048
#define E_   1024   // d_model
#define NST  16
#define RNK  64
#define NPJ  96     // dt_rank + 2*d_state

// ---------------------------------------------------------------------------
// Kernel A: causal conv1d (W=4) + SiLU, transposed write -> u[b][l][d]
// ---------------------------------------------------------------------------
__global__ __launch_bounds__(256) void k_conv(const float* __restrict__ xz,
                                              const float* __restrict__ cw,
                                              const float* __restrict__ cb,
                                              float* __restrict__ u) {
    int l0 = blockIdx.x * 32;
    int d0 = blockIdx.y * 32;
    int b  = blockIdx.z;
    __shared__ float xs[32 * 37];   // [d_in_tile][35 l-values], stride 37 (bank-safe)
    int t = threadIdx.x;
    for (int i = t; i < 32 * 35; i += 256) {
        int dd = i / 35, li = i % 35;
        int gl = l0 - 3 + li;
        float v = 0.f;
        if (gl >= 0) v = xz[((size_t)(b * 2 * D_) + d0 + dd) * L_ + gl];
        xs[dd * 37 + li] = v;
    }
    __syncthreads();
    int dd = t & 31;
    int lg = t >> 5;
    int d  = d0 + dd;
    float w0 = cw[d * 4 + 0], w1 = cw[d * 4 + 1], w2 = cw[d * 4 + 2], w3 = cw[d * 4 + 3];
    float bias = cb[d];
#pragma unroll
    for (int j = 0; j < 4; ++j) {
        int ll = lg * 4 + j;
        float c = bias + w0 * xs[dd * 37 + ll]     + w1 * xs[dd * 37 + ll + 1]
                       + w2 * xs[dd * 37 + ll + 2] + w3 * xs[dd * 37 + ll + 3];
        float s = c / (1.f + __expf(-c));          // silu
        u[((size_t)b * L_ + (l0 + ll)) * D_ + d] = s;
    }
}

// ---------------------------------------------------------------------------
// Kernel B: x_dbl[b][l][r] = sum_d u[b][l][d] * xpw[r][d]   (M=4096,N=96,K=2048)
// one block per (b,l); u-row staged in LDS; 96 threads own one r each
// ---------------------------------------------------------------------------
__global__ __launch_bounds__(128) void k_xdbl(const float* __restrict__ u,
                                              const float* __restrict__ xpw,
                                              float* __restrict__ xdbl) {
    int bl = blockIdx.x;   // b*L + l
    __shared__ float4 us[512];
    int t = threadIdx.x;
    const float4* u4 = (const float4*)(u + (size_t)bl * D_);
    for (int i = t; i < 512; i += 128) us[i] = u4[i];
    __syncthreads();
    if (t < NPJ) {
        const float4* w4 = (const float4*)(xpw + (size_t)t * D_);
        float acc = 0.f;
#pragma unroll 4
        for (int i = 0; i < 512; ++i) {
            float4 a = us[i];
            float4 b = w4[i];
            acc += a.x * b.x + a.y * b.y + a.z * b.z + a.w * b.w;
        }
        xdbl[(size_t)bl * NPJ + t] = acc;
    }
}

// ---------------------------------------------------------------------------
// Kernel C: delta[b][l][d] = softplus(sum_r x_dbl[b][l][r]*dpw[d][r] + dbias[d])
// ---------------------------------------------------------------------------
__global__ __launch_bounds__(256) void k_delta(const float* __restrict__ xdbl,
                                               const float* __restrict__ dpw,
                                               const float* __restrict__ dbias,
                                               float* __restrict__ dlt) {
    int dchunk = blockIdx.x;        // 0..7
    int l = blockIdx.y;
    int b = blockIdx.z;
    size_t bl = (size_t)b * L_ + l;
    __shared__ float4 xd[16];       // 64 floats: x_dbl[..,:64]
    int t = threadIdx.x;
    if (t < 16) xd[t] = ((const float4*)(xdbl + bl * NPJ))[t];
    __syncthreads();
    int d = dchunk * 256 + t;
    const float4* w4 = (const float4*)(dpw + (size_t)d * RNK);
    float acc = dbias[d];
#pragma unroll
    for (int i = 0; i < 16; ++i) {
        float4 a = xd[i];
        float4 b = w4[i];
        acc += a.x * b.x + a.y * b.y + a.z * b.z + a.w * b.w;
    }
    float sp = (acc > 20.f) ? acc : log1pf(__expf(acc));
    dlt[bl * D_ + d] = sp;
}

// ---------------------------------------------------------------------------
// Kernel D: selective scan. thread = (b,d,n); 16-lane reduce over n.
// Epilogue fuses  y += u*D ;  out_z = y*silu(z)  and overwrites dlt as out_z.
// ---------------------------------------------------------------------------
__global__ __launch_bounds__(256) void k_scan(const float* __restrict__ xz,
                                              const float* __restrict__ u,
                                              float* __restrict__ dlt,   // in: delta, out: out_z
                                              const float* __restrict__ xdbl,
                                              const float* __restrict__ Amat,
                                              const float* __restrict__ Dvec) {
    int tid = blockIdx.x * 256 + threadIdx.x;   // 65536 total
    int n     = tid & 15;
    int dglob = tid >> 4;                       // 0..4095
    int d = dglob & (D_ - 1);
    int b = dglob >> 11;
    float a  = Amat[d * NST + n];
    float Dd = Dvec[d];
    const float* zrow = xz + ((size_t)(b * 2 * D_) + D_ + d) * L_;
    float h = 0.f;
    size_t base = (size_t)b * L_;
    for (int l = 0; l < L_; ++l) {
        size_t bl = base + l;
        float dt = dlt[bl * D_ + d];
        float uu = u[bl * D_ + d];
        float Bv = xdbl[bl * NPJ + RNK + n];
        float Cv = xdbl[bl * NPJ + RNK + NST + n];
        h = h * __expf(dt * a) + (dt * uu) * Bv;
        float y = h * Cv;
        y += __shfl_xor(y, 1, 16);
        y += __shfl_xor(y, 2, 16);
        y += __shfl_xor(y, 4, 16);
        y += __shfl_xor(y, 8, 16);
        if (n == 0) {
            float z  = zrow[l];
            float oz = (y + uu * Dd) * (z / (1.f + __expf(-z)));
            dlt[bl * D_ + d] = oz;    // safe: only this group touches [bl][d]
        }
    }
}

// ---------------------------------------------------------------------------
// Kernel E: out[b][l][e] = sum_d out_z[b][l][d] * opw[e][d]
// f32 tiled GEMM: M=4096, N=1024, K=2048; BM=BN=64, BK=32; 4x4 per thread
// ---------------------------------------------------------------------------
#define BM 64
#define BN 64
#define BK 32
__global__ __launch_bounds__(256) void k_out(const float* __restrict__ oz,
                                             const float* __restrict__ opw,
                                             float* __restrict__ out) {
    __shared__ float As[BK * BM];   // [k][m]
    __shared__ float Bs[BK * BN];   // [k][n]
    int t  = threadIdx.x;
    int m0 = blockIdx.x * BM;
    int n0 = blockIdx.y * BN;
    int tx = t & 15, ty = t >> 4;
    float acc[4][4] = {};
    for (int k0 = 0; k0 < 2048; k0 += BK) {
#pragma unroll
        for (int p = 0; p < 2; ++p) {
            int i   = t + p * 256;
            int row = i >> 3, kq = i & 7;
            float4 a4 = *(const float4*)(oz  + ((size_t)(m0 + row)) * 2048 + k0 + kq * 4);
            float4 b4 = *(const float4*)(opw + ((size_t)(n0 + row)) * 2048 + k0 + kq * 4);
            As[(kq * 4 + 0) * BM + row] = a4.x;
            As[(kq * 4 + 1) * BM + row] = a4.y;
            As[(kq * 4 + 2) * BM + row] = a4.z;
            As[(kq * 4 + 3) * BM + row] = a4.w;
            Bs[(kq * 4 + 0) * BN + row] = b4.x;
            Bs[(kq * 4 + 1) * BN + row] = b4.y;
            Bs[(kq * 4 + 2) * BN + row] = b4.z;
            Bs[(kq * 4 + 3) * BN + row] = b4.w;
        }
        __syncthreads();
#pragma unroll
        for (int k = 0; k < BK; ++k) {
            float4 av4 = *(const float4*)&As[k * BM + ty * 4];
            float4 bv4 = *(const float4*)&Bs[k * BN + tx * 4];
            const float* av = (const float*)&av4;
            const float* bv = (const float*)&bv4;
#pragma unroll
            for (int i = 0; i < 4; ++i)
#pragma unroll
                for (int j = 0; j < 4; ++j) acc[i][j] += av[i] * bv[j];
        }
        __syncthreads();
    }
#pragma unroll
    for (int i = 0; i < 4; ++i) {
        float4 o;
        o.x = acc[i][0]; o.y = acc[i][1]; o.z = acc[i][2]; o.w = acc[i][3];
        *(float4*)(out + (size_t)(m0 + ty * 4 + i) * E_ + n0 + tx * 4) = o;
    }
}

// ---------------------------------------------------------------------------
extern "C" void kernel_launch(void* const* d_in, const int* in_sizes, int n_in,
                              void* d_out, int out_size, void* d_ws, size_t ws_size,
                              hipStream_t stream) {
    const float* xz    = (const float*)d_in[0];
    const float* cw    = (const float*)d_in[1];
    const float* cb    = (const float*)d_in[2];
    const float* xpw   = (const float*)d_in[3];
    const float* dpw   = (const float*)d_in[4];
    const float* opw   = (const float*)d_in[5];
    const float* Am    = (const float*)d_in[6];
    const float* Dv    = (const float*)d_in[7];
    const float* dbias = (const float*)d_in[8];
    float* out = (float*)d_out;

    float* ws   = (float*)d_ws;
    float* u    = ws;                 // 8,388,608 f32  (u[b][l][d], silu'd conv)
    float* dlt  = ws + 8388608;       // 8,388,608 f32  (delta -> out_z in place)
    float* xdbl = ws + 16777216;      //   393,216 f32  (x_dbl[b][l][96])

    k_conv <<<dim3(L_ / 32, D_ / 32, B_), 256, 0, stream>>>(xz, cw, cb, u);
    k_xdbl <<<dim3(B_ * L_),             128, 0, stream>>>(u, xpw, xdbl);
    k_delta<<<dim3(8, L_, B_),           256, 0, stream>>>(xdbl, dpw, dbias, dlt);
    k_scan <<<dim3(256),                 256, 0, stream>>>(xz, u, dlt, xdbl, Am, Dv);
    k_out  <<<dim3(4096 / BM, E_ / BN),  256, 0, stream>>>(dlt, opw, out);
}

// Round 2
// 1152.620 us; speedup vs baseline: 1.6884x; 1.6884x over previous
//
#include <hip/hip_runtime.h>
#include <math.h>

#define B_   2
#define D_   2048   // d_inner
#define L_   2048
#define E_   1024   // d_model
#define NST  16
#define RNK  64
#define NPJ  96     // dt_rank + 2*d_state
#define NC   32     // scan chunks
#define CLEN 64     // L_/NC
#define BDN  65536  // B_*D_*NST

// ---------------------------------------------------------------------------
// Kernel A: causal conv1d (W=4) + SiLU, transposed write -> u[b][l][d]
// ---------------------------------------------------------------------------
__global__ __launch_bounds__(256) void k_conv(const float* __restrict__ xz,
                                              const float* __restrict__ cw,
                                              const float* __restrict__ cb,
                                              float* __restrict__ u) {
    int l0 = blockIdx.x * 32;
    int d0 = blockIdx.y * 32;
    int b  = blockIdx.z;
    __shared__ float xs[32 * 37];   // [d_in_tile][35 l-values], stride 37 (bank-safe)
    int t = threadIdx.x;
    for (int i = t; i < 32 * 35; i += 256) {
        int dd = i / 35, li = i % 35;
        int gl = l0 - 3 + li;
        float v = 0.f;
        if (gl >= 0) v = xz[((size_t)(b * 2 * D_) + d0 + dd) * L_ + gl];
        xs[dd * 37 + li] = v;
    }
    __syncthreads();
    int dd = t & 31;
    int lg = t >> 5;
    int d  = d0 + dd;
    float w0 = cw[d * 4 + 0], w1 = cw[d * 4 + 1], w2 = cw[d * 4 + 2], w3 = cw[d * 4 + 3];
    float bias = cb[d];
#pragma unroll
    for (int j = 0; j < 4; ++j) {
        int ll = lg * 4 + j;
        float c = bias + w0 * xs[dd * 37 + ll]     + w1 * xs[dd * 37 + ll + 1]
                       + w2 * xs[dd * 37 + ll + 2] + w3 * xs[dd * 37 + ll + 3];
        float s = c / (1.f + __expf(-c));          // silu
        u[((size_t)b * L_ + (l0 + ll)) * D_ + d] = s;
    }
}

// ---------------------------------------------------------------------------
// Kernel B: x_dbl[b][l][r] = sum_d u[b][l][d] * xpw[r][d]   (M=4096,N=96,K=2048)
// ---------------------------------------------------------------------------
__global__ __launch_bounds__(128) void k_xdbl(const float* __restrict__ u,
                                              const float* __restrict__ xpw,
                                              float* __restrict__ xdbl) {
    int bl = blockIdx.x;   // b*L + l
    __shared__ float4 us[512];
    int t = threadIdx.x;
    const float4* u4 = (const float4*)(u + (size_t)bl * D_);
    for (int i = t; i < 512; i += 128) us[i] = u4[i];
    __syncthreads();
    if (t < NPJ) {
        const float4* w4 = (const float4*)(xpw + (size_t)t * D_);
        float acc = 0.f;
#pragma unroll 4
        for (int i = 0; i < 512; ++i) {
            float4 a = us[i];
            float4 b = w4[i];
            acc += a.x * b.x + a.y * b.y + a.z * b.z + a.w * b.w;
        }
        xdbl[(size_t)bl * NPJ + t] = acc;
    }
}

// ---------------------------------------------------------------------------
// Kernel C: delta[b][l][d] = softplus(sum_r x_dbl[b][l][r]*dpw[d][r] + dbias[d])
// ---------------------------------------------------------------------------
__global__ __launch_bounds__(256) void k_delta(const float* __restrict__ xdbl,
                                               const float* __restrict__ dpw,
                                               const float* __restrict__ dbias,
                                               float* __restrict__ dlt) {
    int dchunk = blockIdx.x;        // 0..7
    int l = blockIdx.y;
    int b = blockIdx.z;
    size_t bl = (size_t)b * L_ + l;
    __shared__ float4 xd[16];       // 64 floats: x_dbl[..,:64]
    int t = threadIdx.x;
    if (t < 16) xd[t] = ((const float4*)(xdbl + bl * NPJ))[t];
    __syncthreads();
    int d = dchunk * 256 + t;
    const float4* w4 = (const float4*)(dpw + (size_t)d * RNK);
    float acc = dbias[d];
#pragma unroll
    for (int i = 0; i < 16; ++i) {
        float4 a = xd[i];
        float4 b = w4[i];
        acc += a.x * b.x + a.y * b.y + a.z * b.z + a.w * b.w;
    }
    float sp = (acc > 20.f) ? acc : log1pf(__expf(acc));
    dlt[bl * D_ + d] = sp;
}

// ---------------------------------------------------------------------------
// Chunked parallel scan.  h[l] = h[l-1]*exp(dt*a) + dt*u*B  over L, split into
// NC chunks of CLEN.  Pass1: per-chunk local scan (h_in=0) -> hend, P.
// Pass2: 32-step inter-chunk scan (hend overwritten in place with h_in).
// Pass3: re-scan each chunk from h_in, reduce over n, fused epilogue.
// thread mapping: n = tid&15 (lane-fast for shfl), dglob = (tid>>4)&4095,
// chunk = tid>>16.  hend/P live in d_out (fully overwritten by k_out later).
// ---------------------------------------------------------------------------
__global__ __launch_bounds__(256) void k_scan1(const float* __restrict__ u,
                                               const float* __restrict__ dlt,
                                               const float* __restrict__ xdbl,
                                               const float* __restrict__ Amat,
                                               float* __restrict__ hend,
                                               float* __restrict__ P) {
    int tid = blockIdx.x * 256 + threadIdx.x;   // 2,097,152 total
    int n     = tid & 15;
    int dglob = (tid >> 4) & 4095;
    int c     = tid >> 16;
    int d = dglob & (D_ - 1);
    int b = dglob >> 11;
    float a = Amat[d * NST + n];
    size_t base = (size_t)b * L_;
    float h = 0.f, s = 0.f;
    int l0 = c * CLEN;
    for (int l = l0; l < l0 + CLEN; ++l) {
        size_t bl = base + l;
        float dt = dlt[bl * D_ + d];
        float uu = u[bl * D_ + d];
        float Bv = xdbl[bl * NPJ + RNK + n];
        float da = dt * a;                 // <= 0 always (a<0, dt>=0)
        s += da;
        h = h * __expf(da) + (dt * uu) * Bv;
    }
    size_t idx = (size_t)c * BDN + (tid & (BDN - 1));
    hend[idx] = h;
    P[idx]    = __expf(s);
}

__global__ __launch_bounds__(256) void k_scan2(float* __restrict__ hend,
                                               const float* __restrict__ P) {
    int bdn = blockIdx.x * 256 + threadIdx.x;   // 65,536 total
    float acc = 0.f;
#pragma unroll
    for (int c = 0; c < NC; ++c) {
        size_t idx = (size_t)c * BDN + bdn;
        float he = hend[idx];
        float pc = P[idx];
        hend[idx] = acc;          // h_in for chunk c
        acc = acc * pc + he;
    }
}

__global__ __launch_bounds__(256) void k_scan3(const float* __restrict__ xz,
                                               const float* __restrict__ u,
                                               float* __restrict__ dlt,   // in: delta, out: out_z
                                               const float* __restrict__ xdbl,
                                               const float* __restrict__ Amat,
                                               const float* __restrict__ Dvec,
                                               const float* __restrict__ hin) {
    int tid = blockIdx.x * 256 + threadIdx.x;
    int n     = tid & 15;
    int dglob = (tid >> 4) & 4095;
    int c     = tid >> 16;
    int d = dglob & (D_ - 1);
    int b = dglob >> 11;
    float a  = Amat[d * NST + n];
    float Dd = Dvec[d];
    const float* zrow = xz + ((size_t)(b * 2 * D_) + D_ + d) * L_;
    size_t base = (size_t)b * L_;
    float h = hin[(size_t)c * BDN + (tid & (BDN - 1))];
    int l0 = c * CLEN;
    for (int l = l0; l < l0 + CLEN; ++l) {
        size_t bl = base + l;
        float dt = dlt[bl * D_ + d];
        float uu = u[bl * D_ + d];
        float Bv = xdbl[bl * NPJ + RNK + n];
        float Cv = xdbl[bl * NPJ + RNK + NST + n];
        h = h * __expf(dt * a) + (dt * uu) * Bv;
        float y = h * Cv;
        y += __shfl_xor(y, 1, 16);
        y += __shfl_xor(y, 2, 16);
        y += __shfl_xor(y, 4, 16);
        y += __shfl_xor(y, 8, 16);
        if (n == 0) {
            float z  = zrow[l];
            float oz = (y + uu * Dd) * (z / (1.f + __expf(-z)));
            dlt[bl * D_ + d] = oz;    // safe: only this lane-group+chunk touches it
        }
    }
}

// ---------------------------------------------------------------------------
// Kernel E: out[b][l][e] = sum_d out_z[b][l][d] * opw[e][d]
// f32 tiled GEMM: M=4096, N=1024, K=2048; BM=BN=64, BK=32; 4x4 per thread
// ---------------------------------------------------------------------------
#define BM 64
#define BN 64
#define BK 32
__global__ __launch_bounds__(256) void k_out(const float* __restrict__ oz,
                                             const float* __restrict__ opw,
                                             float* __restrict__ out) {
    __shared__ float As[BK * BM];   // [k][m]
    __shared__ float Bs[BK * BN];   // [k][n]
    int t  = threadIdx.x;
    int m0 = blockIdx.x * BM;
    int n0 = blockIdx.y * BN;
    int tx = t & 15, ty = t >> 4;
    float acc[4][4] = {};
    for (int k0 = 0; k0 < 2048; k0 += BK) {
#pragma unroll
        for (int p = 0; p < 2; ++p) {
            int i   = t + p * 256;
            int row = i >> 3, kq = i & 7;
            float4 a4 = *(const float4*)(oz  + ((size_t)(m0 + row)) * 2048 + k0 + kq * 4);
            float4 b4 = *(const float4*)(opw + ((size_t)(n0 + row)) * 2048 + k0 + kq * 4);
            As[(kq * 4 + 0) * BM + row] = a4.x;
            As[(kq * 4 + 1) * BM + row] = a4.y;
            As[(kq * 4 + 2) * BM + row] = a4.z;
            As[(kq * 4 + 3) * BM + row] = a4.w;
            Bs[(kq * 4 + 0) * BN + row] = b4.x;
            Bs[(kq * 4 + 1) * BN + row] = b4.y;
            Bs[(kq * 4 + 2) * BN + row] = b4.z;
            Bs[(kq * 4 + 3) * BN + row] = b4.w;
        }
        __syncthreads();
#pragma unroll
        for (int k = 0; k < BK; ++k) {
            float4 av4 = *(const float4*)&As[k * BM + ty * 4];
            float4 bv4 = *(const float4*)&Bs[k * BN + tx * 4];
            const float* av = (const float*)&av4;
            const float* bv = (const float*)&bv4;
#pragma unroll
            for (int i = 0; i < 4; ++i)
#pragma unroll
                for (int j = 0; j < 4; ++j) acc[i][j] += av[i] * bv[j];
        }
        __syncthreads();
    }
#pragma unroll
    for (int i = 0; i < 4; ++i) {
        float4 o;
        o.x = acc[i][0]; o.y = acc[i][1]; o.z = acc[i][2]; o.w = acc[i][3];
        *(float4*)(out + (size_t)(m0 + ty * 4 + i) * E_ + n0 + tx * 4) = o;
    }
}

// ---------------------------------------------------------------------------
extern "C" void kernel_launch(void* const* d_in, const int* in_sizes, int n_in,
                              void* d_out, int out_size, void* d_ws, size_t ws_size,
                              hipStream_t stream) {
    const float* xz    = (const float*)d_in[0];
    const float* cw    = (const float*)d_in[1];
    const float* cb    = (const float*)d_in[2];
    const float* xpw   = (const float*)d_in[3];
    const float* dpw   = (const float*)d_in[4];
    const float* opw   = (const float*)d_in[5];
    const float* Am    = (const float*)d_in[6];
    const float* Dv    = (const float*)d_in[7];
    const float* dbias = (const float*)d_in[8];
    float* out = (float*)d_out;

    float* ws   = (float*)d_ws;
    float* u    = ws;                 // 8,388,608 f32  (u[b][l][d], silu'd conv)
    float* dlt  = ws + 8388608;       // 8,388,608 f32  (delta -> out_z in place)
    float* xdbl = ws + 16777216;      //   393,216 f32  (x_dbl[b][l][96])

    // scan scratch lives in d_out (4,194,304 f32); k_out overwrites it fully
    float* hend = out;                // 2,097,152 f32  [NC][BDN]
    float* P    = out + 2097152;      // 2,097,152 f32  [NC][BDN]

    k_conv <<<dim3(L_ / 32, D_ / 32, B_), 256, 0, stream>>>(xz, cw, cb, u);
    k_xdbl <<<dim3(B_ * L_),             128, 0, stream>>>(u, xpw, xdbl);
    k_delta<<<dim3(8, L_, B_),           256, 0, stream>>>(xdbl, dpw, dbias, dlt);
    k_scan1<<<dim3(8192),                256, 0, stream>>>(u, dlt, xdbl, Am, hend, P);
    k_scan2<<<dim3(256),                 256, 0, stream>>>(hend, P);
    k_scan3<<<dim3(8192),                256, 0, stream>>>(xz, u, dlt, xdbl, Am, Dv, hend);
    k_out  <<<dim3(4096 / BM, E_ / BN),  256, 0, stream>>>(dlt, opw, out);
}

// Round 3
// 626.859 us; speedup vs baseline: 3.1044x; 1.8387x over previous
//
#include <hip/hip_runtime.h>
#include <hip/hip_bf16.h>
#include <math.h>

#define B_   2
#define D_   2048   // d_inner
#define L_   2048
#define E_   1024   // d_model
#define NST  16
#define RNK  64
#define NPJ  96     // dt_rank + 2*d_state
#define NC   32     // scan chunks
#define CLEN 64     // L_/NC
#define BDN  65536  // B_*D_*NST

using short8 = __attribute__((ext_vector_type(8))) short;
using f32x4  = __attribute__((ext_vector_type(4))) float;

// ---------------------------------------------------------------------------
// Kernel A: causal conv1d (W=4) + SiLU, transposed write -> u[b][l][d]
// ---------------------------------------------------------------------------
__global__ __launch_bounds__(256) void k_conv(const float* __restrict__ xz,
                                              const float* __restrict__ cw,
                                              const float* __restrict__ cb,
                                              float* __restrict__ u) {
    int l0 = blockIdx.x * 32;
    int d0 = blockIdx.y * 32;
    int b  = blockIdx.z;
    __shared__ float xs[32 * 37];
    int t = threadIdx.x;
    for (int i = t; i < 32 * 35; i += 256) {
        int dd = i / 35, li = i % 35;
        int gl = l0 - 3 + li;
        float v = 0.f;
        if (gl >= 0) v = xz[((size_t)(b * 2 * D_) + d0 + dd) * L_ + gl];
        xs[dd * 37 + li] = v;
    }
    __syncthreads();
    int dd = t & 31;
    int lg = t >> 5;
    int d  = d0 + dd;
    float w0 = cw[d * 4 + 0], w1 = cw[d * 4 + 1], w2 = cw[d * 4 + 2], w3 = cw[d * 4 + 3];
    float bias = cb[d];
#pragma unroll
    for (int j = 0; j < 4; ++j) {
        int ll = lg * 4 + j;
        float c = bias + w0 * xs[dd * 37 + ll]     + w1 * xs[dd * 37 + ll + 1]
                       + w2 * xs[dd * 37 + ll + 2] + w3 * xs[dd * 37 + ll + 3];
        float s = c / (1.f + __expf(-c));
        u[((size_t)b * L_ + (l0 + ll)) * D_ + d] = s;
    }
}

// ---------------------------------------------------------------------------
// Kernel B: x_dbl = u @ xpw^T   (M=4096, N=96, K=2048), f32 tiled, K-split 8.
// Partials -> xpart[ks][4096][96] (in d_out scratch); k_xred reduces.
// ---------------------------------------------------------------------------
#define XBM 64
#define XBK 64
#define XKS 8
__global__ __launch_bounds__(256) void k_xdbl(const float* __restrict__ u,
                                              const float* __restrict__ xpw,
                                              float* __restrict__ xpart) {
    __shared__ float As[XBM][XBK + 4];   // pad: rows 2-way banked (free)
    __shared__ float Ws[NPJ][XBK + 4];   // pad: <=4-way on reads
    int t  = threadIdx.x;
    int m0 = blockIdx.x * XBM;
    int ks = blockIdx.y;
    int tx = t & 15;      // n: cols tx*6 .. +6
    int ty = t >> 4;      // m: rows ty*4 .. +4
    float acc[4][6] = {};
    for (int k0 = ks * 256; k0 < ks * 256 + 256; k0 += XBK) {
#pragma unroll
        for (int p = 0; p < 4; ++p) {            // A: 64x64 f32
            int slot = t + p * 256;
            int row = slot >> 4, c4 = slot & 15;
            *(float4*)&As[row][c4 * 4] =
                *(const float4*)(u + (size_t)(m0 + row) * 2048 + k0 + c4 * 4);
        }
#pragma unroll
        for (int p = 0; p < 6; ++p) {            // W: 96x64 f32
            int slot = t + p * 256;
            int row = slot >> 4, c4 = slot & 15;
            *(float4*)&Ws[row][c4 * 4] =
                *(const float4*)(xpw + (size_t)row * 2048 + k0 + c4 * 4);
        }
        __syncthreads();
#pragma unroll
        for (int k4 = 0; k4 < XBK / 4; ++k4) {
            float4 av[4]; float4 wv[6];
#pragma unroll
            for (int i = 0; i < 4; ++i) av[i] = *(float4*)&As[ty * 4 + i][k4 * 4];
#pragma unroll
            for (int j = 0; j < 6; ++j) wv[j] = *(float4*)&Ws[tx * 6 + j][k4 * 4];
#pragma unroll
            for (int i = 0; i < 4; ++i)
#pragma unroll
                for (int j = 0; j < 6; ++j)
                    acc[i][j] += av[i].x * wv[j].x + av[i].y * wv[j].y
                               + av[i].z * wv[j].z + av[i].w * wv[j].w;
        }
        __syncthreads();
    }
#pragma unroll
    for (int i = 0; i < 4; ++i)
#pragma unroll
        for (int j = 0; j < 6; ++j)
            xpart[((size_t)ks * 4096 + m0 + ty * 4 + i) * NPJ + tx * 6 + j] = acc[i][j];
}

__global__ __launch_bounds__(256) void k_xred(const float* __restrict__ xpart,
                                              float* __restrict__ xdbl) {
    int i = blockIdx.x * 256 + threadIdx.x;      // 98304 float4 slots
    float4 s = ((const float4*)xpart)[i];
#pragma unroll
    for (int ks = 1; ks < XKS; ++ks) {
        float4 p = ((const float4*)(xpart + (size_t)ks * 393216))[i];
        s.x += p.x; s.y += p.y; s.z += p.z; s.w += p.w;
    }
    ((float4*)xdbl)[i] = s;
}

// ---------------------------------------------------------------------------
// Kernel C: delta = softplus(x_dbl[:, :64] @ dpw^T + dbias)
// ---------------------------------------------------------------------------
__global__ __launch_bounds__(256) void k_delta(const float* __restrict__ xdbl,
                                               const float* __restrict__ dpw,
                                               const float* __restrict__ dbias,
                                               float* __restrict__ dlt) {
    int dchunk = blockIdx.x;
    int l = blockIdx.y;
    int b = blockIdx.z;
    size_t bl = (size_t)b * L_ + l;
    __shared__ float4 xd[16];
    int t = threadIdx.x;
    if (t < 16) xd[t] = ((const float4*)(xdbl + bl * NPJ))[t];
    __syncthreads();
    int d = dchunk * 256 + t;
    const float4* w4 = (const float4*)(dpw + (size_t)d * RNK);
    float acc = dbias[d];
#pragma unroll
    for (int i = 0; i < 16; ++i) {
        float4 a = xd[i];
        float4 b2 = w4[i];
        acc += a.x * b2.x + a.y * b2.y + a.z * b2.z + a.w * b2.w;
    }
    float sp = (acc > 20.f) ? acc : log1pf(__expf(acc));
    dlt[bl * D_ + d] = sp;
}

// ---------------------------------------------------------------------------
// Chunked parallel scan (3 passes). hend/P in d_out scratch.
// ---------------------------------------------------------------------------
__global__ __launch_bounds__(256) void k_scan1(const float* __restrict__ u,
                                               const float* __restrict__ dlt,
                                               const float* __restrict__ xdbl,
                                               const float* __restrict__ Amat,
                                               float* __restrict__ hend,
                                               float* __restrict__ P) {
    int tid = blockIdx.x * 256 + threadIdx.x;
    int n     = tid & 15;
    int dglob = (tid >> 4) & 4095;
    int c     = tid >> 16;
    int d = dglob & (D_ - 1);
    int b = dglob >> 11;
    float a = Amat[d * NST + n];
    size_t base = (size_t)b * L_;
    float h = 0.f, s = 0.f;
    int l0 = c * CLEN;
    for (int l = l0; l < l0 + CLEN; ++l) {
        size_t bl = base + l;
        float dt = dlt[bl * D_ + d];
        float uu = u[bl * D_ + d];
        float Bv = xdbl[bl * NPJ + RNK + n];
        float da = dt * a;
        s += da;
        h = h * __expf(da) + (dt * uu) * Bv;
    }
    size_t idx = (size_t)c * BDN + (tid & (BDN - 1));
    hend[idx] = h;
    P[idx]    = __expf(s);
}

__global__ __launch_bounds__(256) void k_scan2(float* __restrict__ hend,
                                               const float* __restrict__ P) {
    int bdn = blockIdx.x * 256 + threadIdx.x;
    float acc = 0.f;
#pragma unroll
    for (int c = 0; c < NC; ++c) {
        size_t idx = (size_t)c * BDN + bdn;
        float he = hend[idx];
        float pc = P[idx];
        hend[idx] = acc;
        acc = acc * pc + he;
    }
}

__global__ __launch_bounds__(256) void k_scan3(const float* __restrict__ xz,
                                               const float* __restrict__ u,
                                               float* __restrict__ dlt,   // in: delta, out: out_z (f32)
                                               const float* __restrict__ xdbl,
                                               const float* __restrict__ Amat,
                                               const float* __restrict__ Dvec,
                                               const float* __restrict__ hin) {
    int tid = blockIdx.x * 256 + threadIdx.x;
    int n     = tid & 15;
    int dglob = (tid >> 4) & 4095;
    int c     = tid >> 16;
    int d = dglob & (D_ - 1);
    int b = dglob >> 11;
    float a  = Amat[d * NST + n];
    float Dd = Dvec[d];
    const float* zrow = xz + ((size_t)(b * 2 * D_) + D_ + d) * L_;
    size_t base = (size_t)b * L_;
    float h = hin[(size_t)c * BDN + (tid & (BDN - 1))];
    int l0 = c * CLEN;
    for (int l = l0; l < l0 + CLEN; ++l) {
        size_t bl = base + l;
        float dt = dlt[bl * D_ + d];
        float uu = u[bl * D_ + d];
        float Bv = xdbl[bl * NPJ + RNK + n];
        float Cv = xdbl[bl * NPJ + RNK + NST + n];
        h = h * __expf(dt * a) + (dt * uu) * Bv;
        float y = h * Cv;
        y += __shfl_xor(y, 1, 16);
        y += __shfl_xor(y, 2, 16);
        y += __shfl_xor(y, 4, 16);
        y += __shfl_xor(y, 8, 16);
        if (n == 0) {
            float z  = zrow[l];
            float oz = (y + uu * Dd) * (z / (1.f + __expf(-z)));
            dlt[bl * D_ + d] = oz;
        }
    }
}

// ---------------------------------------------------------------------------
// Pack: out_z (f32, dlt) -> bf16 ozb; opw (f32) -> bf16 wb. Both in dead u region.
// ---------------------------------------------------------------------------
__global__ __launch_bounds__(256) void k_pack(const float* __restrict__ oz,
                                              const float* __restrict__ opw,
                                              __hip_bfloat16* __restrict__ ozb,
                                              __hip_bfloat16* __restrict__ wb) {
    const int NOZ4 = 2097152;   // 8,388,608 / 4
    const int NW4  = 524288;    // 2,097,152 / 4
    int stride = gridDim.x * 256;
    for (int i = blockIdx.x * 256 + threadIdx.x; i < NOZ4 + NW4; i += stride) {
        float4 v; __hip_bfloat16* dst;
        if (i < NOZ4) { v = ((const float4*)oz)[i];  dst = ozb + (size_t)i * 4; }
        else { int j = i - NOZ4; v = ((const float4*)opw)[j]; dst = wb + (size_t)j * 4; }
        __hip_bfloat16 b0 = __float2bfloat16(v.x), b1 = __float2bfloat16(v.y);
        __hip_bfloat16 b2 = __float2bfloat16(v.z), b3 = __float2bfloat16(v.w);
        ushort4 o = make_ushort4(*(unsigned short*)&b0, *(unsigned short*)&b1,
                                 *(unsigned short*)&b2, *(unsigned short*)&b3);
        *(ushort4*)dst = o;
    }
}

// ---------------------------------------------------------------------------
// Kernel E: out = out_z @ opw^T, bf16 MFMA (16x16x32), 128x64 tile, 4 waves.
// A=ozb [4096][2048] K-major, B=wb [1024][2048] K-major (B^T recipe).
// ---------------------------------------------------------------------------
#define OBM 128
#define OBN 64
__global__ __launch_bounds__(256) void k_out(const __hip_bfloat16* __restrict__ ozb,
                                             const __hip_bfloat16* __restrict__ wb,
                                             float* __restrict__ out) {
    __shared__ __hip_bfloat16 As[OBM * 32];   // [128][32] linear, 8KB
    __shared__ __hip_bfloat16 Bs[OBN * 32];   // [64][32] linear, 4KB
    int t  = threadIdx.x;
    int m0 = blockIdx.x * OBM;
    int n0 = blockIdx.y * OBN;
    int wv = t >> 6;
    int ln = t & 63;
    int wr = wv >> 1, wc = wv & 1;
    f32x4 acc[4][2] = {};
    for (int k0 = 0; k0 < 2048; k0 += 32) {
#pragma unroll
        for (int p = 0; p < 2; ++p) {           // A: 8KB = 2 issues/wave
            int eidx = (wv * 2 + p) * 512 + ln * 8;
            int row = eidx >> 5, col = eidx & 31;
            __builtin_amdgcn_global_load_lds(
                (const __attribute__((address_space(1))) void*)(ozb + (size_t)(m0 + row) * 2048 + k0 + col),
                (__attribute__((address_space(3))) void*)(As + (wv * 2 + p) * 512),
                16, 0, 0);
        }
        {                                        // B: 4KB = 1 issue/wave
            int eidx = wv * 512 + ln * 8;
            int row = eidx >> 5, col = eidx & 31;
            __builtin_amdgcn_global_load_lds(
                (const __attribute__((address_space(1))) void*)(wb + (size_t)(n0 + row) * 2048 + k0 + col),
                (__attribute__((address_space(3))) void*)(Bs + wv * 512),
                16, 0, 0);
        }
        __syncthreads();
        short8 af[4], bf[2];
#pragma unroll
        for (int m = 0; m < 4; ++m)
            af[m] = *(const short8*)(As + (wr * 64 + m * 16 + (ln & 15)) * 32 + ((ln >> 4) * 8));
#pragma unroll
        for (int n = 0; n < 2; ++n)
            bf[n] = *(const short8*)(Bs + (wc * 32 + n * 16 + (ln & 15)) * 32 + ((ln >> 4) * 8));
#pragma unroll
        for (int m = 0; m < 4; ++m)
#pragma unroll
            for (int n = 0; n < 2; ++n)
                acc[m][n] = __builtin_amdgcn_mfma_f32_16x16x32_bf16(af[m], bf[n], acc[m][n], 0, 0, 0);
        __syncthreads();
    }
    // C/D layout: col = lane&15, row = (lane>>4)*4 + reg   [m89/m91-verified]
#pragma unroll
    for (int m = 0; m < 4; ++m)
#pragma unroll
        for (int n = 0; n < 2; ++n) {
            int col   = n0 + wc * 32 + n * 16 + (ln & 15);
            int rbase = m0 + wr * 64 + m * 16 + (ln >> 4) * 4;
#pragma unroll
            for (int r = 0; r < 4; ++r)
                out[(size_t)(rbase + r) * E_ + col] = acc[m][n][r];
        }
}

// ---------------------------------------------------------------------------
extern "C" void kernel_launch(void* const* d_in, const int* in_sizes, int n_in,
                              void* d_out, int out_size, void* d_ws, size_t ws_size,
                              hipStream_t stream) {
    const float* xz    = (const float*)d_in[0];
    const float* cw    = (const float*)d_in[1];
    const float* cb    = (const float*)d_in[2];
    const float* xpw   = (const float*)d_in[3];
    const float* dpw   = (const float*)d_in[4];
    const float* opw   = (const float*)d_in[5];
    const float* Am    = (const float*)d_in[6];
    const float* Dv    = (const float*)d_in[7];
    const float* dbias = (const float*)d_in[8];
    float* out = (float*)d_out;

    float* ws   = (float*)d_ws;
    float* u    = ws;                 // 8,388,608 f32
    float* dlt  = ws + 8388608;       // 8,388,608 f32 (delta -> out_z)
    float* xdbl = ws + 16777216;      //   393,216 f32

    // d_out scratch (fully overwritten by k_out at the end):
    float* xpart = out;               // XKS*393,216 = 3,145,728 f32 (dead after k_xred)
    float* hend  = out;               // 2,097,152 f32
    float* P     = out + 2097152;     // 2,097,152 f32

    // bf16 staging in dead u region (after scan3):
    __hip_bfloat16* ozb = (__hip_bfloat16*)u;                 // 8,388,608 bf16
    __hip_bfloat16* wb  = (__hip_bfloat16*)(ws + 4194304);    // 2,097,152 bf16

    k_conv <<<dim3(L_ / 32, D_ / 32, B_), 256, 0, stream>>>(xz, cw, cb, u);
    k_xdbl <<<dim3(4096 / XBM, XKS),     256, 0, stream>>>(u, xpw, xpart);
    k_xred <<<dim3(384),                 256, 0, stream>>>(xpart, xdbl);
    k_delta<<<dim3(8, L_, B_),           256, 0, stream>>>(xdbl, dpw, dbias, dlt);
    k_scan1<<<dim3(8192),                256, 0, stream>>>(u, dlt, xdbl, Am, hend, P);
    k_scan2<<<dim3(256),                 256, 0, stream>>>(hend, P);
    k_scan3<<<dim3(8192),                256, 0, stream>>>(xz, u, dlt, xdbl, Am, Dv, hend);
    k_pack <<<dim3(1024),                256, 0, stream>>>(dlt, opw, ozb, wb);
    k_out  <<<dim3(4096 / OBM, E_ / OBN), 256, 0, stream>>>(ozb, wb, out);
}